// Round 7
// baseline (108.382 us; speedup 1.0000x reference)
//
#include <hip/hip_runtime.h>

#define B_ 8
#define T_ 2048
#define D_ 512
#define NTPB 72    /* block-tiles per batch: sum_{i=0..7} (2i+2) */

typedef float f32x16 __attribute__((ext_vector_type(16)));
typedef __bf16 bf16x8 __attribute__((ext_vector_type(8)));

// order-preserving float<->uint encoding for atomicMax on possibly-negative floats
__device__ __forceinline__ unsigned encf(float f) {
    int i = __float_as_int(f);
    return (i < 0) ? ~((unsigned)i) : (((unsigned)i) | 0x80000000u);
}
__device__ __forceinline__ float decf(unsigned u) {
    unsigned b = (u & 0x80000000u) ? (u ^ 0x80000000u) : ~u;
    return __int_as_float((int)b);
}

// Kernel 1: xn[row] = bf16(x[row] / max(||x[row]||,1e-12)); init msim to enc(-1)
__global__ __launch_bounds__(256) void rownorm_kernel(
        const float* __restrict__ x, __bf16* __restrict__ xn,
        unsigned* __restrict__ msim) {
    int row  = blockIdx.x * 4 + (threadIdx.x >> 6);
    int lane = threadIdx.x & 63;
    const float* p = x + (size_t)row * D_ + lane * 8;
    float4 a = *(const float4*)p;
    float4 b = *(const float4*)(p + 4);
    float ss = a.x*a.x + a.y*a.y + a.z*a.z + a.w*a.w
             + b.x*b.x + b.y*b.y + b.z*b.z + b.w*b.w;
#pragma unroll
    for (int m = 32; m; m >>= 1) ss += __shfl_xor(ss, m);
    float r = 1.0f / fmaxf(sqrtf(ss), 1e-12f);
    bf16x8 h;
    h[0] = (__bf16)(a.x * r); h[1] = (__bf16)(a.y * r);
    h[2] = (__bf16)(a.z * r); h[3] = (__bf16)(a.w * r);
    h[4] = (__bf16)(b.x * r); h[5] = (__bf16)(b.y * r);
    h[6] = (__bf16)(b.z * r); h[7] = (__bf16)(b.w * r);
    *(bf16x8*)(xn + (size_t)row * D_ + lane * 8) = h;
    if (lane == 0) msim[row] = 0x407FFFFFu;   // encf(-1.0f)
}

// Kernel 2: wave-autonomous, spill-proof. Block = 4 independent waves (2x2)
// over a 256x128 block-tile; each wave computes a 128x64 tile of the causal
// cosine-sim max with mfma_32x32x16, fragments loaded global->VGPR into
// NAMED registers (no arrays indexed by loop vars -> no scratch), depth-2
// k-pipeline. No LDS, no barriers. Diag-straddle masked in epilogue.
__global__ __launch_bounds__(256, 2) void simmax_kernel(
        const __bf16* __restrict__ xn, unsigned* __restrict__ msim) {
    int bid = blockIdx.x;
    int b   = bid & 7;        // batch -> XCD (round-robin dispatch)
    int t   = bid >> 3;       // 0..71 block-tile id
    int i = 0;
    while ((i + 1) * (i + 2) <= t) i++;   // i(i+1) <= t < (i+1)(i+2)
    int j = t - i * (i + 1);              // 0..2i+1
    const bool strad = (j >= 2 * i);      // col-chunk straddles the diagonal

    int tid = threadIdx.x;
    int w   = tid >> 6;       // 0..3
    int wr  = w >> 1;         // row-half of block-tile
    int wc  = w & 1;          // col-half
    int ln  = tid & 63;
    int lr  = ln & 31;        // A-row / B-col within 32
    int hc  = ln >> 5;        // k-half selector

    int r0    = i * 256 + wr * 128;       // wave's first row (in batch)
    int c0    = j * 128 + wc * 64;        // wave's first col (in batch)
    const char* xb = (const char*)xn;
    unsigned baseA = ((unsigned)(b * T_ + r0 + lr) * D_ + hc * 8) * 2;
    unsigned baseB = ((unsigned)(b * T_ + c0 + lr) * D_ + hc * 8) * 2;

    // 8 named accumulators (128 regs) — wave tile 128x64 = 4x2 of 32x32
    f32x16 c00, c01, c10, c11, c20, c21, c30, c31;
#pragma unroll
    for (int r = 0; r < 16; r++) {
        c00[r] = 0.f; c01[r] = 0.f; c10[r] = 0.f; c11[r] = 0.f;
        c20[r] = 0.f; c21[r] = 0.f; c30[r] = 0.f; c31[r] = 0.f;
    }

    // two named prefetch sets (6 frags each); k-step byte stride = 32
    bf16x8 pa0, pa1, pa2, pa3, pb0, pb1;
    bf16x8 qa0, qa1, qa2, qa3, qb0, qb1;

#define LOADSET(s, k) do {                                                  \
    s##a0 = *(const bf16x8*)(xb + baseA +         (k) * 32);                \
    s##a1 = *(const bf16x8*)(xb + baseA + 32768 + (k) * 32);                \
    s##a2 = *(const bf16x8*)(xb + baseA + 65536 + (k) * 32);                \
    s##a3 = *(const bf16x8*)(xb + baseA + 98304 + (k) * 32);                \
    s##b0 = *(const bf16x8*)(xb + baseB +         (k) * 32);                \
    s##b1 = *(const bf16x8*)(xb + baseB + 32768 + (k) * 32);                \
} while (0)

#define MFMASET(s) do {                                                     \
    c00 = __builtin_amdgcn_mfma_f32_32x32x16_bf16(s##a0, s##b0, c00, 0,0,0);\
    c01 = __builtin_amdgcn_mfma_f32_32x32x16_bf16(s##a0, s##b1, c01, 0,0,0);\
    c10 = __builtin_amdgcn_mfma_f32_32x32x16_bf16(s##a1, s##b0, c10, 0,0,0);\
    c11 = __builtin_amdgcn_mfma_f32_32x32x16_bf16(s##a1, s##b1, c11, 0,0,0);\
    c20 = __builtin_amdgcn_mfma_f32_32x32x16_bf16(s##a2, s##b0, c20, 0,0,0);\
    c21 = __builtin_amdgcn_mfma_f32_32x32x16_bf16(s##a2, s##b1, c21, 0,0,0);\
    c30 = __builtin_amdgcn_mfma_f32_32x32x16_bf16(s##a3, s##b0, c30, 0,0,0);\
    c31 = __builtin_amdgcn_mfma_f32_32x32x16_bf16(s##a3, s##b1, c31, 0,0,0);\
} while (0)

    LOADSET(p, 0);
    LOADSET(q, 1);
    for (int k = 0; k < 32; k += 2) {
        MFMASET(p);
        if (k + 2 < 32) LOADSET(p, k + 2);
        MFMASET(q);
        if (k + 3 < 32) LOADSET(q, k + 3);
    }
#undef LOADSET
#undef MFMASET

    // epilogue: C/D layout (m74/m101): col = lane&31,
    // row = (reg&3) + 8*(reg>>2) + 4*(lane>>5)
    unsigned* mbase = msim + (size_t)b * T_ + r0;
    const float NINF = -__builtin_inff();
    int gcol0 = c0 + lr;                  // col of ni=0; ni=1 adds 32

#define EPI(mi, cA, cB) do {                                                \
    _Pragma("unroll")                                                       \
    for (int r = 0; r < 16; r++) {                                          \
        int rloc = (mi) * 32 + (r & 3) + 8 * (r >> 2) + 4 * hc;             \
        int grow = r0 + rloc;                                               \
        float t0 = cA[r], t1 = cB[r];                                       \
        if (strad) {                                                        \
            if (gcol0      >= grow) t0 = NINF;                              \
            if (gcol0 + 32 >= grow) t1 = NINF;                              \
        }                                                                   \
        float v = fmaxf(t0, t1);                                            \
        v = fmaxf(v, __shfl_xor(v, 1));                                     \
        v = fmaxf(v, __shfl_xor(v, 2));                                     \
        v = fmaxf(v, __shfl_xor(v, 4));                                     \
        v = fmaxf(v, __shfl_xor(v, 8));                                     \
        v = fmaxf(v, __shfl_xor(v, 16));                                    \
        if (lr == 0) atomicMax(&mbase[rloc], encf(v));                      \
    }                                                                       \
} while (0)

    EPI(0, c00, c01);
    EPI(1, c10, c11);
    EPI(2, c20, c21);
    EPI(3, c30, c31);
#undef EPI
}

// Kernel 3: out = gelu_tanh(x * (1-alpha + alpha*exp(-tau*max_sim)))
__global__ __launch_bounds__(256) void gelu_kernel(
        const float* __restrict__ x, const unsigned* __restrict__ msim,
        const float* __restrict__ ltau, const float* __restrict__ lblend,
        float* __restrict__ out) {
    int i = blockIdx.x * 256 + threadIdx.x;   // float4 index
    float tau   = __expf(ltau[0]);
    float alpha = 1.f / (1.f + __expf(-lblend[0]));
    int row = i >> 7;                          // D_/4 = 128 float4 per row
    float ms = decf(msim[row]);
    float sc = (1.f - alpha) + alpha * __expf(-tau * ms);
    float4 v = ((const float4*)x)[i];
    const float c0 = 0.7978845608028654f;
    const float c1 = 0.044715f;
    float4 o;
#pragma unroll
    for (int k = 0; k < 4; k++) {
        float z = ((const float*)&v)[k] * sc;
        float u = c0 * (z + c1 * z * z * z);
        float e = __expf(2.f * u);
        float th = 1.f - 2.f / (e + 1.f);      // tanh, inf-safe
        ((float*)&o)[k] = 0.5f * z * (1.f + th);
    }
    ((float4*)out)[i] = o;
}

extern "C" void kernel_launch(void* const* d_in, const int* in_sizes, int n_in,
                              void* d_out, int out_size, void* d_ws, size_t ws_size,
                              hipStream_t stream) {
    (void)in_sizes; (void)n_in; (void)out_size; (void)ws_size;
    const float* x      = (const float*)d_in[0];
    const float* ltau   = (const float*)d_in[1];
    const float* lblend = (const float*)d_in[2];
    float*    out   = (float*)d_out;
    // xn (16.8 MB) lives in d_out until gelu overwrites it; msim in ws.
    __bf16*   xn    = (__bf16*)d_out;
    unsigned* msim  = (unsigned*)d_ws;

    rownorm_kernel<<<B_ * T_ / 4, 256, 0, stream>>>(x, xn, msim);
    simmax_kernel<<<B_ * NTPB, 256, 0, stream>>>(xn, msim);
    gelu_kernel<<<(B_ * T_ * D_ / 4) / 256, 256, 0, stream>>>(x, msim, ltau, lblend, out);
}

// Round 8
// 88.735 us; speedup vs baseline: 1.2214x; 1.2214x over previous
//
#include <hip/hip_runtime.h>

#define B_ 8
#define T_ 2048
#define D_ 512
#define NTPB 72    /* block-tiles per batch: sum_{i=0..7} (2i+2) */

typedef float f32x16 __attribute__((ext_vector_type(16)));
typedef __bf16 bf16x8 __attribute__((ext_vector_type(8)));

// order-preserving float<->uint encoding for atomicMax on possibly-negative floats
__device__ __forceinline__ unsigned encf(float f) {
    int i = __float_as_int(f);
    return (i < 0) ? ~((unsigned)i) : (((unsigned)i) | 0x80000000u);
}
__device__ __forceinline__ float decf(unsigned u) {
    unsigned b = (u & 0x80000000u) ? (u ^ 0x80000000u) : ~u;
    return __int_as_float((int)b);
}

// Kernel 1: normalize rows and store in MFMA-FRAGMENT-PACKED layout:
// xnp[panel][ks][lane], panel = 32 rows, ks = k-step of 16, lane 0..63,
// 16B per lane: lane l = xn[panel*32 + (l&31)][ks*16 + (l>>5)*8 + e].
// A wave's fragment load in simmax is then one contiguous 1KB dwordx4.
__global__ __launch_bounds__(256) void rownorm_kernel(
        const float* __restrict__ x, char* __restrict__ xnp,
        unsigned* __restrict__ msim) {
    int row  = blockIdx.x * 4 + (threadIdx.x >> 6);
    int lane = threadIdx.x & 63;
    const float* p = x + (size_t)row * D_ + lane * 8;
    float4 a = *(const float4*)p;
    float4 b = *(const float4*)(p + 4);
    float ss = a.x*a.x + a.y*a.y + a.z*a.z + a.w*a.w
             + b.x*b.x + b.y*b.y + b.z*b.z + b.w*b.w;
#pragma unroll
    for (int m = 32; m; m >>= 1) ss += __shfl_xor(ss, m);
    float r = 1.0f / fmaxf(sqrtf(ss), 1e-12f);
    bf16x8 h;
    h[0] = (__bf16)(a.x * r); h[1] = (__bf16)(a.y * r);
    h[2] = (__bf16)(a.z * r); h[3] = (__bf16)(a.w * r);
    h[4] = (__bf16)(b.x * r); h[5] = (__bf16)(b.y * r);
    h[6] = (__bf16)(b.z * r); h[7] = (__bf16)(b.w * r);
    // cols [lane*8, lane*8+8) -> ks = lane>>1, hc = lane&1
    int ks = lane >> 1, hc = lane & 1;
    unsigned off = ((unsigned)(row >> 5) << 15) + (unsigned)ks * 1024
                 + (((row & 31) + (hc << 5)) << 4);
    *(bf16x8*)(xnp + off) = h;
    if (lane == 0) msim[row] = 0x407FFFFFu;   // encf(-1.0f)
}

// Kernel 2: wave-autonomous. Block = 4 independent waves (2x2) over a
// 256x128 block-tile; each wave computes a 128x64 tile of the causal
// cosine-sim max with mfma_32x32x16. Fragments come straight from the
// packed layout: one coalesced 1KB load each. Named regs only (no
// dynamic indexing), depth-2 k-pipeline, no LDS, no barriers.
__global__ __launch_bounds__(256, 2) void simmax_kernel(
        const char* __restrict__ xnp, unsigned* __restrict__ msim) {
    int bid = blockIdx.x;
    int b   = bid & 7;        // batch -> XCD (round-robin dispatch)
    int t   = bid >> 3;       // 0..71 block-tile id
    int i = 0;
    while ((i + 1) * (i + 2) <= t) i++;   // i(i+1) <= t < (i+1)(i+2)
    int j = t - i * (i + 1);              // 0..2i+1
    const bool strad = (j >= 2 * i);      // col-chunk straddles the diagonal

    int tid = threadIdx.x;
    int w   = tid >> 6;       // 0..3
    int wr  = w >> 1;         // row-half of block-tile
    int wc  = w & 1;          // col-half
    int ln  = tid & 63;
    int lr  = ln & 31;
    int hc  = ln >> 5;

    int r0 = i * 256 + wr * 128;          // wave's first row (in batch)
    int c0 = j * 128 + wc * 64;           // wave's first col (in batch)
    // packed: row panel stride 32KB == rows*1024 (r0,c0 are 32-multiples)
    unsigned baseA = (unsigned)(b * T_ + r0) * 1024u + (unsigned)ln * 16u;
    unsigned baseB = (unsigned)(b * T_ + c0) * 1024u + (unsigned)ln * 16u;

    // 8 named accumulators (128 AGPRs) — wave tile 128x64 = 4x2 of 32x32
    f32x16 c00, c01, c10, c11, c20, c21, c30, c31;
#pragma unroll
    for (int r = 0; r < 16; r++) {
        c00[r] = 0.f; c01[r] = 0.f; c10[r] = 0.f; c11[r] = 0.f;
        c20[r] = 0.f; c21[r] = 0.f; c30[r] = 0.f; c31[r] = 0.f;
    }

    // two named prefetch sets (6 frags each); ks byte stride = 1024
    bf16x8 pa0, pa1, pa2, pa3, pb0, pb1;
    bf16x8 qa0, qa1, qa2, qa3, qb0, qb1;

#define LOADSET(s, k) do {                                                  \
    s##a0 = *(const bf16x8*)(xnp + baseA +          (k) * 1024);            \
    s##a1 = *(const bf16x8*)(xnp + baseA + 32768  + (k) * 1024);            \
    s##a2 = *(const bf16x8*)(xnp + baseA + 65536  + (k) * 1024);            \
    s##a3 = *(const bf16x8*)(xnp + baseA + 98304  + (k) * 1024);            \
    s##b0 = *(const bf16x8*)(xnp + baseB +          (k) * 1024);            \
    s##b1 = *(const bf16x8*)(xnp + baseB + 32768  + (k) * 1024);            \
} while (0)

#define MFMASET(s) do {                                                     \
    c00 = __builtin_amdgcn_mfma_f32_32x32x16_bf16(s##a0, s##b0, c00, 0,0,0);\
    c01 = __builtin_amdgcn_mfma_f32_32x32x16_bf16(s##a0, s##b1, c01, 0,0,0);\
    c10 = __builtin_amdgcn_mfma_f32_32x32x16_bf16(s##a1, s##b0, c10, 0,0,0);\
    c11 = __builtin_amdgcn_mfma_f32_32x32x16_bf16(s##a1, s##b1, c11, 0,0,0);\
    c20 = __builtin_amdgcn_mfma_f32_32x32x16_bf16(s##a2, s##b0, c20, 0,0,0);\
    c21 = __builtin_amdgcn_mfma_f32_32x32x16_bf16(s##a2, s##b1, c21, 0,0,0);\
    c30 = __builtin_amdgcn_mfma_f32_32x32x16_bf16(s##a3, s##b0, c30, 0,0,0);\
    c31 = __builtin_amdgcn_mfma_f32_32x32x16_bf16(s##a3, s##b1, c31, 0,0,0);\
} while (0)

    LOADSET(p, 0);
    LOADSET(q, 1);
    for (int k = 0; k < 32; k += 2) {
        MFMASET(p);
        if (k + 2 < 32) LOADSET(p, k + 2);
        MFMASET(q);
        if (k + 3 < 32) LOADSET(q, k + 3);
    }
#undef LOADSET
#undef MFMASET

    // epilogue: C/D layout (m74/m101, HW-verified rounds 6/7): col = lane&31,
    // row = (reg&3) + 8*(reg>>2) + 4*(lane>>5)
    unsigned* mbase = msim + (size_t)b * T_ + r0;
    const float NINF = -__builtin_inff();
    int gcol0 = c0 + lr;                  // col of ni=0; ni=1 adds 32

#define EPI(mi, cA, cB) do {                                                \
    _Pragma("unroll")                                                       \
    for (int r = 0; r < 16; r++) {                                          \
        int rloc = (mi) * 32 + (r & 3) + 8 * (r >> 2) + 4 * hc;             \
        int grow = r0 + rloc;                                               \
        float t0 = cA[r], t1 = cB[r];                                       \
        if (strad) {                                                        \
            if (gcol0      >= grow) t0 = NINF;                              \
            if (gcol0 + 32 >= grow) t1 = NINF;                              \
        }                                                                   \
        float v = fmaxf(t0, t1);                                            \
        v = fmaxf(v, __shfl_xor(v, 1));                                     \
        v = fmaxf(v, __shfl_xor(v, 2));                                     \
        v = fmaxf(v, __shfl_xor(v, 4));                                     \
        v = fmaxf(v, __shfl_xor(v, 8));                                     \
        v = fmaxf(v, __shfl_xor(v, 16));                                    \
        if (lr == 0) atomicMax(&mbase[rloc], encf(v));                      \
    }                                                                       \
} while (0)

    EPI(0, c00, c01);
    EPI(1, c10, c11);
    EPI(2, c20, c21);
    EPI(3, c30, c31);
#undef EPI
}

// Kernel 3: out = gelu_tanh(x * (1-alpha + alpha*exp(-tau*max_sim)))
__global__ __launch_bounds__(256) void gelu_kernel(
        const float* __restrict__ x, const unsigned* __restrict__ msim,
        const float* __restrict__ ltau, const float* __restrict__ lblend,
        float* __restrict__ out) {
    int i = blockIdx.x * 256 + threadIdx.x;   // float4 index
    float tau   = __expf(ltau[0]);
    float alpha = 1.f / (1.f + __expf(-lblend[0]));
    int row = i >> 7;                          // D_/4 = 128 float4 per row
    float ms = decf(msim[row]);
    float sc = (1.f - alpha) + alpha * __expf(-tau * ms);
    float4 v = ((const float4*)x)[i];
    const float c0 = 0.7978845608028654f;
    const float c1 = 0.044715f;
    float4 o;
#pragma unroll
    for (int k = 0; k < 4; k++) {
        float z = ((const float*)&v)[k] * sc;
        float u = c0 * (z + c1 * z * z * z);
        float e = __expf(2.f * u);
        float th = 1.f - 2.f / (e + 1.f);      // tanh, inf-safe
        ((float*)&o)[k] = 0.5f * z * (1.f + th);
    }
    ((float4*)out)[i] = o;
}

extern "C" void kernel_launch(void* const* d_in, const int* in_sizes, int n_in,
                              void* d_out, int out_size, void* d_ws, size_t ws_size,
                              hipStream_t stream) {
    (void)in_sizes; (void)n_in; (void)out_size; (void)ws_size;
    const float* x      = (const float*)d_in[0];
    const float* ltau   = (const float*)d_in[1];
    const float* lblend = (const float*)d_in[2];
    float*    out   = (float*)d_out;
    // xnp (packed normalized bf16, 16.8 MB) lives in d_out until gelu
    // overwrites it; msim in ws.
    char*     xnp   = (char*)d_out;
    unsigned* msim  = (unsigned*)d_ws;

    rownorm_kernel<<<B_ * T_ / 4, 256, 0, stream>>>(x, xnp, msim);
    simmax_kernel<<<B_ * NTPB, 256, 0, stream>>>(xnp, msim);
    gelu_kernel<<<(B_ * T_ * D_ / 4) / 256, 256, 0, stream>>>(x, msim, ltau, lblend, out);
}

// Round 9
// 70.610 us; speedup vs baseline: 1.5349x; 1.2567x over previous
//
#include <hip/hip_runtime.h>

#define B_ 8
#define T_ 2048
#define D_ 512
#define BT 128
#define NT (T_/BT)              /* 16  */
#define NTILES (NT*(NT+1)/2)    /* 136 */
#define KTILES 8                /* K-tiles of 64 (4 ks-steps of 16 each) */

typedef float f32x16 __attribute__((ext_vector_type(16)));
typedef __bf16 bf16x8 __attribute__((ext_vector_type(8)));

// order-preserving float<->uint encoding for atomicMax on possibly-negative floats
__device__ __forceinline__ unsigned encf(float f) {
    int i = __float_as_int(f);
    return (i < 0) ? ~((unsigned)i) : (((unsigned)i) | 0x80000000u);
}
__device__ __forceinline__ float decf(unsigned u) {
    unsigned b = (u & 0x80000000u) ? (u ^ 0x80000000u) : ~u;
    return __int_as_float((int)b);
}

__device__ __forceinline__ void gload_lds16(const char* g, char* l) {
    __builtin_amdgcn_global_load_lds(
        (const __attribute__((address_space(1))) unsigned int*)g,
        (__attribute__((address_space(3))) unsigned int*)l, 16, 0, 0);
}

// Kernel 1: normalize rows, store in MFMA-FRAGMENT-PACKED layout (verified r8):
// xnp[panel][ks][fl*16B]: panel = 32 rows, ks = k-step of 16;
// frag lane fl holds row panel*32+(fl&31), k = ks*16 + (fl>>5)*8 + e.
__global__ __launch_bounds__(256) void rownorm_kernel(
        const float* __restrict__ x, char* __restrict__ xnp,
        unsigned* __restrict__ msim) {
    int row  = blockIdx.x * 4 + (threadIdx.x >> 6);
    int lane = threadIdx.x & 63;
    const float* p = x + (size_t)row * D_ + lane * 8;
    float4 a = *(const float4*)p;
    float4 b = *(const float4*)(p + 4);
    float ss = a.x*a.x + a.y*a.y + a.z*a.z + a.w*a.w
             + b.x*b.x + b.y*b.y + b.z*b.z + b.w*b.w;
#pragma unroll
    for (int m = 32; m; m >>= 1) ss += __shfl_xor(ss, m);
    float r = 1.0f / fmaxf(sqrtf(ss), 1e-12f);
    bf16x8 h;
    h[0] = (__bf16)(a.x * r); h[1] = (__bf16)(a.y * r);
    h[2] = (__bf16)(a.z * r); h[3] = (__bf16)(a.w * r);
    h[4] = (__bf16)(b.x * r); h[5] = (__bf16)(b.y * r);
    h[6] = (__bf16)(b.z * r); h[7] = (__bf16)(b.w * r);
    int ks = lane >> 1, hc = lane & 1;
    unsigned off = ((unsigned)(row >> 5) << 15) + (unsigned)ks * 1024
                 + (((row & 31) + (hc << 5)) << 4);
    *(bf16x8*)(xnp + off) = h;
    if (lane == 0) msim[row] = 0x407FFFFFu;   // encf(-1.0f)
}

// Kernel 2: one block per (batch, lower-tri 128x128 tile). 4 waves (2x2),
// each a 64x64 sub-tile via mfma_32x32x16 (4 named accs). r2's proven
// 2-barrier single-buffer loop; staging/reads use the packed layout:
// pass q stages panel q, wave w handles ks=w -> linear gload_lds dest,
// fully-coalesced 1KB sources, conflict-free contiguous ds_read_b128.
__global__ __launch_bounds__(256, 3) void simmax_kernel(
        const char* __restrict__ xnp, unsigned* __restrict__ msim) {
    __shared__ __attribute__((aligned(16))) char sA[16384];
    __shared__ __attribute__((aligned(16))) char sB[16384];

    int bid = blockIdx.x;
    int b   = bid & 7;        // batch -> XCD (round-robin dispatch)
    int s   = bid >> 3;       // 0..135 linear lower-tri tile id
    int it  = 0;
    while ((it + 1) * (it + 2) / 2 <= s) it++;
    int jt  = s - it * (it + 1) / 2;
    const bool diag = (it == jt);

    int tid = threadIdx.x;
    int ln  = tid & 63;
    int w   = tid >> 6;       // 0..3
    int wr  = w >> 1;         // wave row (64 rows)
    int wc  = w & 1;          // wave col (64 cols)
    int lr  = ln & 31;        // B-col within 32 (C col = lane&31)
    int hc  = ln >> 5;

    const char* gAb = xnp + (size_t)(b * T_ + it * BT) * 1024;
    const char* gBb = xnp + (size_t)(b * T_ + jt * BT) * 1024;

    f32x16 c00, c01, c10, c11;    // 64 AGPR: wave tile 64x64 = 2x2 of 32x32
#pragma unroll
    for (int r = 0; r < 16; r++) {
        c00[r] = 0.f; c01[r] = 0.f; c10[r] = 0.f; c11[r] = 0.f;
    }

    // stage: pass q = panel q; wave w = ks w. dst wave-uniform + lane*16.
#define STAGE_A(kc) do {                                                    \
    _Pragma("unroll")                                                       \
    for (int q = 0; q < 4; q++)                                             \
        gload_lds16(gAb + q * 32768 + ((kc) * 4 + w) * 1024 + ln * 16,      \
                    sA + q * 4096 + w * 1024 + ln * 16);                    \
} while (0)
#define STAGE_B(kc) do {                                                    \
    _Pragma("unroll")                                                       \
    for (int q = 0; q < 4; q++)                                             \
        gload_lds16(gBb + q * 32768 + ((kc) * 4 + w) * 1024 + ln * 16,      \
                    sB + q * 4096 + w * 1024 + ln * 16);                    \
} while (0)

    const char* bB = diag ? sA : sB;
    int aoff = (wr * 2) * 4096 + ln * 16;   // panel wr*2 + mi
    int boff = (wc * 2) * 4096 + ln * 16;   // panel wc*2 + ni

    for (int kc = 0; kc < KTILES; kc++) {
        __syncthreads();                    // LDS safe to overwrite
        STAGE_A(kc);
        if (!diag) STAGE_B(kc);
        __syncthreads();                    // staged (vmcnt0 before barrier)
#pragma unroll
        for (int kk = 0; kk < 4; kk++) {
            bf16x8 a0 = *(const bf16x8*)(sA + aoff +        kk * 1024);
            bf16x8 a1 = *(const bf16x8*)(sA + aoff + 4096 + kk * 1024);
            bf16x8 b0 = *(const bf16x8*)(bB + boff +        kk * 1024);
            bf16x8 b1 = *(const bf16x8*)(bB + boff + 4096 + kk * 1024);
            c00 = __builtin_amdgcn_mfma_f32_32x32x16_bf16(a0, b0, c00, 0, 0, 0);
            c01 = __builtin_amdgcn_mfma_f32_32x32x16_bf16(a0, b1, c01, 0, 0, 0);
            c10 = __builtin_amdgcn_mfma_f32_32x32x16_bf16(a1, b0, c10, 0, 0, 0);
            c11 = __builtin_amdgcn_mfma_f32_32x32x16_bf16(a1, b1, c11, 0, 0, 0);
        }
    }
#undef STAGE_A
#undef STAGE_B

    // epilogue: C/D layout (HW-verified r6-r8): col = lane&31,
    // row = (r&3) + 8*(r>>2) + 4*hc. Diag tiles mask cloc >= rloc.
    unsigned* mrow = msim + (size_t)b * T_ + it * BT + wr * 64;
    const float NINF = -__builtin_inff();

#define EPI(mi, cA, cB) do {                                                \
    _Pragma("unroll")                                                       \
    for (int r = 0; r < 16; r++) {                                          \
        int crow = (r & 3) + 8 * (r >> 2) + 4 * hc;                         \
        int rloc = wr * 64 + (mi) * 32 + crow;      /* within tile */       \
        float t0 = cA[r], t1 = cB[r];                                       \
        if (diag) {                                                         \
            int cl0 = wc * 64 + lr;                                         \
            if (cl0      >= rloc) t0 = NINF;                                \
            if (cl0 + 32 >= rloc) t1 = NINF;                                \
        }                                                                   \
        float v = fmaxf(t0, t1);                                            \
        v = fmaxf(v, __shfl_xor(v, 1));                                     \
        v = fmaxf(v, __shfl_xor(v, 2));                                     \
        v = fmaxf(v, __shfl_xor(v, 4));                                     \
        v = fmaxf(v, __shfl_xor(v, 8));                                     \
        v = fmaxf(v, __shfl_xor(v, 16));                                    \
        if (lr == 0) atomicMax(&mrow[(mi) * 32 + crow], encf(v));           \
    }                                                                       \
} while (0)

    EPI(0, c00, c01);
    EPI(1, c10, c11);
#undef EPI
}

// Kernel 3: out = gelu_tanh(x * (1-alpha + alpha*exp(-tau*max_sim)))
__global__ __launch_bounds__(256) void gelu_kernel(
        const float* __restrict__ x, const unsigned* __restrict__ msim,
        const float* __restrict__ ltau, const float* __restrict__ lblend,
        float* __restrict__ out) {
    int i = blockIdx.x * 256 + threadIdx.x;   // float4 index
    float tau   = __expf(ltau[0]);
    float alpha = 1.f / (1.f + __expf(-lblend[0]));
    int row = i >> 7;                          // D_/4 = 128 float4 per row
    float ms = decf(msim[row]);
    float sc = (1.f - alpha) + alpha * __expf(-tau * ms);
    float4 v = ((const float4*)x)[i];
    const float c0 = 0.7978845608028654f;
    const float c1 = 0.044715f;
    float4 o;
#pragma unroll
    for (int k = 0; k < 4; k++) {
        float z = ((const float*)&v)[k] * sc;
        float u = c0 * (z + c1 * z * z * z);
        float e = __expf(2.f * u);
        float th = 1.f - 2.f / (e + 1.f);      // tanh, inf-safe
        ((float*)&o)[k] = 0.5f * z * (1.f + th);
    }
    ((float4*)out)[i] = o;
}

extern "C" void kernel_launch(void* const* d_in, const int* in_sizes, int n_in,
                              void* d_out, int out_size, void* d_ws, size_t ws_size,
                              hipStream_t stream) {
    (void)in_sizes; (void)n_in; (void)out_size; (void)ws_size;
    const float* x      = (const float*)d_in[0];
    const float* ltau   = (const float*)d_in[1];
    const float* lblend = (const float*)d_in[2];
    float*    out   = (float*)d_out;
    // xnp (packed normalized bf16, 16.8 MB) lives in d_out until gelu
    // overwrites it; msim (64 KB) in ws.
    char*     xnp   = (char*)d_out;
    unsigned* msim  = (unsigned*)d_ws;

    rownorm_kernel<<<B_ * T_ / 4, 256, 0, stream>>>(x, xnp, msim);
    simmax_kernel<<<B_ * NTILES, 256, 0, stream>>>(xnp, msim);
    gelu_kernel<<<(B_ * T_ * D_ / 4) / 256, 256, 0, stream>>>(x, msim, ltau, lblend, out);
}

// Round 11
// 67.009 us; speedup vs baseline: 1.6174x; 1.0537x over previous
//
#include <hip/hip_runtime.h>

#define B_ 8
#define T_ 2048
#define D_ 512

typedef float f32x16 __attribute__((ext_vector_type(16)));
typedef __bf16 bf16x8 __attribute__((ext_vector_type(8)));

// order-preserving float<->uint encoding for atomicMax on floats
__device__ __forceinline__ unsigned encf(float f) {
    int i = __float_as_int(f);
    return (i < 0) ? ~((unsigned)i) : (((unsigned)i) | 0x80000000u);
}
__device__ __forceinline__ float decf(unsigned u) {
    unsigned b = (u & 0x80000000u) ? (u ^ 0x80000000u) : ~u;
    return __int_as_float((int)b);
}

__device__ __forceinline__ void gload_lds16(const char* g, char* l) {
    __builtin_amdgcn_global_load_lds(
        (const __attribute__((address_space(1))) unsigned int*)g,
        (__attribute__((address_space(3))) unsigned int*)l, 16, 0, 0);
}

// Kernel 1: pack RAW x into bf16 MFMA-fragment layout (verified r8/r9):
// line (panel,ks) = 1KB; frag lane fl holds row panel*32+(fl&31),
// k = ks*16 + (fl>>5)*8 + e.  Also rnorm[row] and msim sentinel init.
// LDS-transpose so global reads AND writes are fully coalesced.
// FIX r10: panel = 32 KB (32 lines), sP was half-sized and write-out
// only covered 16 KB -> k>=256 was stale garbage.
__global__ __launch_bounds__(256) void pack_kernel(
        const float* __restrict__ x, char* __restrict__ xnp,
        unsigned* __restrict__ msim, float* __restrict__ rnorm) {
    __shared__ __attribute__((aligned(16))) char sP[32768];
    int blk = blockIdx.x;            // global 32-row panel id (512 blocks)
    int t   = threadIdx.x;
    int ln  = t & 63, w = t >> 6;

#pragma unroll
    for (int q = 0; q < 8; q++) {
        int row32 = q * 4 + w;       // wave-uniform row within panel
        const float* p = x + ((size_t)blk * 32 + row32) * D_ + ln * 8;
        float4 a = *(const float4*)p;
        float4 c = *(const float4*)(p + 4);
        float ss = a.x*a.x + a.y*a.y + a.z*a.z + a.w*a.w
                 + c.x*c.x + c.y*c.y + c.z*c.z + c.w*c.w;
#pragma unroll
        for (int m = 32; m; m >>= 1) ss += __shfl_xor(ss, m);
        if (ln == 0)
            rnorm[blk * 32 + row32] = 1.0f / fmaxf(sqrtf(ss), 1e-12f);
        bf16x8 h;                    // RAW (normalization deferred)
        h[0] = (__bf16)a.x; h[1] = (__bf16)a.y;
        h[2] = (__bf16)a.z; h[3] = (__bf16)a.w;
        h[4] = (__bf16)c.x; h[5] = (__bf16)c.y;
        h[6] = (__bf16)c.z; h[7] = (__bf16)c.w;
        int ks = ln >> 1, hcw = ln & 1;
        int slot = row32 + hcw * 32;
        int off = ks * 1024 + ((slot * 16) ^ ((ks & 7) << 4));  // swizzled
        *(bf16x8*)(sP + off) = h;
    }
    if (t < 32) msim[blk * 32 + t] = encf(-1e30f);   // sentinel (row-0 case)
    __syncthreads();
#pragma unroll
    for (int iq = 0; iq < 8; iq++) {                 // coalesced write-out
        int beta = iq * 4096 + t * 16;               // full 32 KB panel
        int ks = beta >> 10;
        bf16x8 v = *(const bf16x8*)(sP + ks * 1024 +
                     ((beta & 1023) ^ ((ks & 7) << 4)));
        *(bf16x8*)(xnp + (size_t)blk * 32768 + beta) = v;
    }
}

// Kernel 2: persistent row-panel simmax. Block = 4 waves (2x2) = 128-row
// panel i, processes a chunk of 2 j-tiles (128 cols each). A fragments
// global->registers (coalesced 1KB packed lines); B staged via single
// 16KB LDS buffer, 2-barrier loop. Per-j-tile fold of G*rn_j into
// register running max; ONE atomic pass per block. rn_i applied in gelu.
__global__ __launch_bounds__(256, 2) void simmax_kernel(
        const char* __restrict__ xnp, const float* __restrict__ rnorm,
        unsigned* __restrict__ msim) {
    __shared__ __attribute__((aligned(16))) char sB[16384];

    int bid = blockIdx.x;
    int b   = bid & 7;               // batch -> XCD
    int u   = 71 - (bid >> 3);       // reversed: big-i (full) chunks first
    int i = 0, cum = 0;
    while (cum + ((i + 2) >> 1) <= u) { cum += (i + 2) >> 1; i++; }
    int j0 = 2 * (u - cum);          // chunk covers j-tiles {j0, j0+1} ∩ [0,i]

    int t  = threadIdx.x;
    int ln = t & 63, w = t >> 6;
    int wr = w >> 1, wc = w & 1;
    int lr = ln & 31, hc = ln >> 5;
    const float NINF = -__builtin_inff();

    const char*  gA  = xnp + (size_t)(b * 64 + i * 4 + wr * 2) * 32768;
    const float* rnc = rnorm + b * T_;

    f32x16 c00, c01, c10, c11, rm0, rm1;
#pragma unroll
    for (int r = 0; r < 16; r++) {
        c00[r] = 0.f; c01[r] = 0.f; c10[r] = 0.f; c11[r] = 0.f;
        rm0[r] = NINF; rm1[r] = NINF;
    }

    for (int jj = 0; jj < 2; jj++) {
        int j = j0 + jj;
        if (j > i) break;
        const char* gB = xnp + (size_t)(b * 64 + j * 4) * 32768;
        for (int kc = 0; kc < 8; kc++) {
            __syncthreads();         // previous compute done, LDS reusable
#pragma unroll
            for (int q = 0; q < 4; q++)   // wave w stages ks=w, 4 col-panels
                gload_lds16(gB + q * 32768 + (kc * 4 + w) * 1024 + ln * 16,
                            sB + q * 4096 + w * 1024 + ln * 16);
            bf16x8 aF[2][4];              // A: global->reg, coalesced 1KB
#pragma unroll
            for (int p = 0; p < 2; p++)
#pragma unroll
                for (int ks = 0; ks < 4; ks++)
                    aF[p][ks] = *(const bf16x8*)(gA + p * 32768 +
                                  (kc * 4 + ks) * 1024 + ln * 16);
            __syncthreads();         // B staged + A landed (vmcnt0)
            const char* bb = sB + (wc * 2) * 4096 + ln * 16;
#pragma unroll
            for (int ks = 0; ks < 4; ks++) {
                bf16x8 b0 = *(const bf16x8*)(bb + ks * 1024);
                bf16x8 b1 = *(const bf16x8*)(bb + 4096 + ks * 1024);
                c00 = __builtin_amdgcn_mfma_f32_32x32x16_bf16(aF[0][ks], b0, c00, 0, 0, 0);
                c01 = __builtin_amdgcn_mfma_f32_32x32x16_bf16(aF[0][ks], b1, c01, 0, 0, 0);
                c10 = __builtin_amdgcn_mfma_f32_32x32x16_bf16(aF[1][ks], b0, c10, 0, 0, 0);
                c11 = __builtin_amdgcn_mfma_f32_32x32x16_bf16(aF[1][ks], b1, c11, 0, 0, 0);
            }
        }
        // fold j-tile into running max: val = G * rn_col (order-preserving)
        float rnj0 = rnc[j * 128 + wc * 64 + lr];
        float rnj1 = rnc[j * 128 + wc * 64 + lr + 32];
        bool dt = (j == i);          // diagonal tile -> causal mask
#pragma unroll
        for (int r = 0; r < 16; r++) {
            int crow = (r & 3) + 8 * (r >> 2) + 4 * hc;
            int cl   = wc * 64 + lr;
            {   // rows wr*64 + crow  (A panel 0)
                int rloc = wr * 64 + crow;
                float t0 = c00[r] * rnj0, t1 = c01[r] * rnj1;
                if (dt) { if (cl >= rloc) t0 = NINF; if (cl + 32 >= rloc) t1 = NINF; }
                rm0[r] = fmaxf(rm0[r], fmaxf(t0, t1));
                c00[r] = 0.f; c01[r] = 0.f;
            }
            {   // rows wr*64 + 32 + crow  (A panel 1)
                int rloc = wr * 64 + 32 + crow;
                float t0 = c10[r] * rnj0, t1 = c11[r] * rnj1;
                if (dt) { if (cl >= rloc) t0 = NINF; if (cl + 32 >= rloc) t1 = NINF; }
                rm1[r] = fmaxf(rm1[r], fmaxf(t0, t1));
                c10[r] = 0.f; c11[r] = 0.f;
            }
        }
    }

    // epilogue: cross-lane max over 32 cols, one atomic pass per block
    unsigned* mrow = msim + (size_t)b * T_ + i * 128 + wr * 64;
#pragma unroll
    for (int r = 0; r < 16; r++) {
        int crow = (r & 3) + 8 * (r >> 2) + 4 * hc;
        float v = rm0[r];
        v = fmaxf(v, __shfl_xor(v, 1));
        v = fmaxf(v, __shfl_xor(v, 2));
        v = fmaxf(v, __shfl_xor(v, 4));
        v = fmaxf(v, __shfl_xor(v, 8));
        v = fmaxf(v, __shfl_xor(v, 16));
        if (lr == 0) atomicMax(&mrow[crow], encf(v));
        float v2 = rm1[r];
        v2 = fmaxf(v2, __shfl_xor(v2, 1));
        v2 = fmaxf(v2, __shfl_xor(v2, 2));
        v2 = fmaxf(v2, __shfl_xor(v2, 4));
        v2 = fmaxf(v2, __shfl_xor(v2, 8));
        v2 = fmaxf(v2, __shfl_xor(v2, 16));
        if (lr == 0) atomicMax(&mrow[32 + crow], encf(v2));
    }
}

// Kernel 3: out = gelu_tanh(x * (1-alpha + alpha*exp(-tau*max_sim)));
// max_sim = stored * rn_row (row 0: sentinel -> -1.0 per nan_to_num).
__global__ __launch_bounds__(256) void gelu_kernel(
        const float* __restrict__ x, const unsigned* __restrict__ msim,
        const float* __restrict__ rnorm,
        const float* __restrict__ ltau, const float* __restrict__ lblend,
        float* __restrict__ out) {
    int i = blockIdx.x * 256 + threadIdx.x;   // float4 index
    float tau   = __expf(ltau[0]);
    float alpha = 1.f / (1.f + __expf(-lblend[0]));
    int row = i >> 7;                          // D_/4 = 128 float4 per row
    float raw = decf(msim[row]);
    float ms  = (raw < -1e29f) ? -1.0f : raw * rnorm[row];
    float sc = (1.f - alpha) + alpha * __expf(-tau * ms);
    float4 v = ((const float4*)x)[i];
    const float c0 = 0.7978845608028654f;
    const float c1 = 0.044715f;
    float4 o;
#pragma unroll
    for (int k = 0; k < 4; k++) {
        float z = ((const float*)&v)[k] * sc;
        float u = c0 * (z + c1 * z * z * z);
        float e = __expf(2.f * u);
        float th = 1.f - 2.f / (e + 1.f);      // tanh, inf-safe
        ((float*)&o)[k] = 0.5f * z * (1.f + th);
    }
    ((float4*)out)[i] = o;
}

extern "C" void kernel_launch(void* const* d_in, const int* in_sizes, int n_in,
                              void* d_out, int out_size, void* d_ws, size_t ws_size,
                              hipStream_t stream) {
    (void)in_sizes; (void)n_in; (void)out_size; (void)ws_size;
    const float* x      = (const float*)d_in[0];
    const float* ltau   = (const float*)d_in[1];
    const float* lblend = (const float*)d_in[2];
    float*    out   = (float*)d_out;
    // xnp (packed raw bf16, 16.8 MB) lives in d_out until gelu overwrites;
    // ws: msim (64 KB) + rnorm (64 KB).
    char*     xnp   = (char*)d_out;
    unsigned* msim  = (unsigned*)d_ws;
    float*    rnorm = (float*)((char*)d_ws + 65536);

    pack_kernel<<<B_ * T_ / 32, 256, 0, stream>>>(x, xnp, msim, rnorm);
    simmax_kernel<<<B_ * 72, 256, 0, stream>>>(xnp, rnorm, msim);
    gelu_kernel<<<(B_ * T_ * D_ / 4) / 256, 256, 0, stream>>>(
        x, msim, rnorm, ltau, lblend, out);
}

// Round 12
// 66.319 us; speedup vs baseline: 1.6343x; 1.0104x over previous
//
#include <hip/hip_runtime.h>

#define B_ 8
#define T_ 2048
#define D_ 512

typedef float f32x16 __attribute__((ext_vector_type(16)));
typedef __bf16 bf16x8 __attribute__((ext_vector_type(8)));

// order-preserving float<->uint encoding for atomicMax on floats
__device__ __forceinline__ unsigned encf(float f) {
    int i = __float_as_int(f);
    return (i < 0) ? ~((unsigned)i) : (((unsigned)i) | 0x80000000u);
}
__device__ __forceinline__ float decf(unsigned u) {
    unsigned b = (u & 0x80000000u) ? (u ^ 0x80000000u) : ~u;
    return __int_as_float((int)b);
}

__device__ __forceinline__ void gload_lds16(const char* g, char* l) {
    __builtin_amdgcn_global_load_lds(
        (const __attribute__((address_space(1))) unsigned int*)g,
        (__attribute__((address_space(3))) unsigned int*)l, 16, 0, 0);
}

// Kernel 1: pack RAW x into bf16 MFMA-fragment layout (verified r8-r11):
// line (panel,ks) = 1KB; frag lane fl holds row panel*32+(fl&31),
// k = ks*16 + (fl>>5)*8 + e.  Also rnorm[row] and msim sentinel init.
__global__ __launch_bounds__(256) void pack_kernel(
        const float* __restrict__ x, char* __restrict__ xnp,
        unsigned* __restrict__ msim, float* __restrict__ rnorm) {
    __shared__ __attribute__((aligned(16))) char sP[32768];
    int blk = blockIdx.x;            // global 32-row panel id (512 blocks)
    int t   = threadIdx.x;
    int ln  = t & 63, w = t >> 6;

#pragma unroll
    for (int q = 0; q < 8; q++) {
        int row32 = q * 4 + w;       // wave-uniform row within panel
        const float* p = x + ((size_t)blk * 32 + row32) * D_ + ln * 8;
        float4 a = *(const float4*)p;
        float4 c = *(const float4*)(p + 4);
        float ss = a.x*a.x + a.y*a.y + a.z*a.z + a.w*a.w
                 + c.x*c.x + c.y*c.y + c.z*c.z + c.w*c.w;
#pragma unroll
        for (int m = 32; m; m >>= 1) ss += __shfl_xor(ss, m);
        if (ln == 0)
            rnorm[blk * 32 + row32] = 1.0f / fmaxf(sqrtf(ss), 1e-12f);
        bf16x8 h;                    // RAW (normalization deferred)
        h[0] = (__bf16)a.x; h[1] = (__bf16)a.y;
        h[2] = (__bf16)a.z; h[3] = (__bf16)a.w;
        h[4] = (__bf16)c.x; h[5] = (__bf16)c.y;
        h[6] = (__bf16)c.z; h[7] = (__bf16)c.w;
        int ks = ln >> 1, hcw = ln & 1;
        int slot = row32 + hcw * 32;
        int off = ks * 1024 + ((slot * 16) ^ ((ks & 7) << 4));  // swizzled
        *(bf16x8*)(sP + off) = h;
    }
    if (t < 32) msim[blk * 32 + t] = encf(-1e30f);   // sentinel (row-0 case)
    __syncthreads();
#pragma unroll
    for (int iq = 0; iq < 8; iq++) {                 // coalesced write-out
        int beta = iq * 4096 + t * 16;               // full 32 KB panel
        int ks = beta >> 10;
        bf16x8 v = *(const bf16x8*)(sP + ks * 1024 +
                     ((beta & 1023) ^ ((ks & 7) << 4)));
        *(bf16x8*)(xnp + (size_t)blk * 32768 + beta) = v;
    }
}

// Kernel 2: ZERO-BARRIER steady state. Block = (batch, 128-col strip j,
// 256-row chunk c). Prologue: whole B col-panel (4 packed panels = 128KB)
// -> LDS once, ONE barrier. Then 8 waves, each owning one 32-row panel,
// stream A global->reg (coalesced 1KB lines) with 4 MFMA/k-step against
// LDS-resident B. No barriers, no staging in the loop -> compiler
// pipelines freely. Epilogue: fold G*rn_col, causal mask, 1 atomic pass.
__global__ __launch_bounds__(512, 1) void simmax_kernel(
        const char* __restrict__ xnp, const float* __restrict__ rnorm,
        unsigned* __restrict__ msim) {
    __shared__ __attribute__((aligned(16))) char sB[131072];

    int bid = blockIdx.x;
    int b   = bid & 7;               // batch -> XCD (round-robin)
    int u   = bid >> 3;              // 0..71; 0-63 full chunks, 64-71 partial
    int j, c;
    if (u >= 64) {                   // partial chunks last (backfill)
        int p = u - 64; j = 2 * p + 1; c = 7 - p;
    } else {                         // full chunks: F_j = (16-j)>>1
        j = 0; int acc = 0;
        while (acc + ((16 - j) >> 1) <= u) { acc += (16 - j) >> 1; j++; }
        c = u - acc;
    }
    int c0  = j * 128;               // strip's first col
    int rp0 = c0 + c * 256;          // chunk's first row

    int t  = threadIdx.x;
    int ln = t & 63, w = t >> 6;     // 8 waves
    int lr = ln & 31, hc = ln >> 5;
    const float NINF = -__builtin_inff();

    // prologue: B col-panel (panels 4j..4j+3, contiguous 128KB) -> LDS
    const char* gB = xnp + (size_t)(b * 64 + j * 4) * 32768;
#pragma unroll
    for (int q = 0; q < 16; q++) {
        int L = w * 16 + q;          // line 0..127
        gload_lds16(gB + L * 1024 + ln * 16, sB + L * 1024 + ln * 16);
    }
    __syncthreads();                 // drains vmcnt; the ONLY barrier

    int myr = rp0 + 32 * w;          // this wave's row-panel start
    if (myr < T_) {
        const char* gA = xnp + (size_t)(b * 64 + (myr >> 5)) * 32768 + ln * 16;
        const char* lB = sB + ln * 16;
        f32x16 a0, a1, a2, a3;
#pragma unroll
        for (int r = 0; r < 16; r++) { a0[r]=0.f; a1[r]=0.f; a2[r]=0.f; a3[r]=0.f; }

#pragma unroll 8
        for (int k = 0; k < 32; k++) {
            bf16x8 av = *(const bf16x8*)(gA + k * 1024);
            bf16x8 b0 = *(const bf16x8*)(lB +          k * 1024);
            bf16x8 b1 = *(const bf16x8*)(lB + 32768  + k * 1024);
            bf16x8 b2 = *(const bf16x8*)(lB + 65536  + k * 1024);
            bf16x8 b3 = *(const bf16x8*)(lB + 98304  + k * 1024);
            a0 = __builtin_amdgcn_mfma_f32_32x32x16_bf16(av, b0, a0, 0, 0, 0);
            a1 = __builtin_amdgcn_mfma_f32_32x32x16_bf16(av, b1, a1, 0, 0, 0);
            a2 = __builtin_amdgcn_mfma_f32_32x32x16_bf16(av, b2, a2, 0, 0, 0);
            a3 = __builtin_amdgcn_mfma_f32_32x32x16_bf16(av, b3, a3, 0, 0, 0);
        }

        // epilogue: val = G * rn_col (order-preserving, rn>0); causal mask;
        // cross-lane max over 32 cols/tile; one atomicMax per row.
        const float* rnc = rnorm + b * T_;
        float rn0 = rnc[c0 + lr],      rn1 = rnc[c0 + 32 + lr];
        float rn2 = rnc[c0 + 64 + lr], rn3 = rnc[c0 + 96 + lr];
        bool dt = (c0 + 127 >= myr);   // tile straddles/above diagonal
        unsigned* mrow = msim + (size_t)b * T_ + myr;
#pragma unroll
        for (int r = 0; r < 16; r++) {
            int crow = (r & 3) + 8 * (r >> 2) + 4 * hc;
            int row  = myr + crow;
            float t0 = a0[r] * rn0, t1 = a1[r] * rn1;
            float t2 = a2[r] * rn2, t3 = a3[r] * rn3;
            if (dt) {                  // mask cols >= row (triu k=0)
                if (c0 + lr      >= row) t0 = NINF;
                if (c0 + 32 + lr >= row) t1 = NINF;
                if (c0 + 64 + lr >= row) t2 = NINF;
                if (c0 + 96 + lr >= row) t3 = NINF;
            }
            float v = fmaxf(fmaxf(t0, t1), fmaxf(t2, t3));
            v = fmaxf(v, __shfl_xor(v, 1));
            v = fmaxf(v, __shfl_xor(v, 2));
            v = fmaxf(v, __shfl_xor(v, 4));
            v = fmaxf(v, __shfl_xor(v, 8));
            v = fmaxf(v, __shfl_xor(v, 16));
            if (lr == 0) atomicMax(&mrow[crow], encf(v));
        }
    }
}

// Kernel 3: out = gelu_tanh(x * (1-alpha + alpha*exp(-tau*max_sim)));
// max_sim = stored * rn_row (row 0: sentinel -> -1.0 per nan_to_num).
__global__ __launch_bounds__(256) void gelu_kernel(
        const float* __restrict__ x, const unsigned* __restrict__ msim,
        const float* __restrict__ rnorm,
        const float* __restrict__ ltau, const float* __restrict__ lblend,
        float* __restrict__ out) {
    int i = blockIdx.x * 256 + threadIdx.x;   // float4 index
    float tau   = __expf(ltau[0]);
    float alpha = 1.f / (1.f + __expf(-lblend[0]));
    int row = i >> 7;                          // D_/4 = 128 float4 per row
    float raw = decf(msim[row]);
    float ms  = (raw < -1e29f) ? -1.0f : raw * rnorm[row];
    float sc = (1.f - alpha) + alpha * __expf(-tau * ms);
    float4 v = ((const float4*)x)[i];
    const float c0 = 0.7978845608028654f;
    const float c1 = 0.044715f;
    float4 o;
#pragma unroll
    for (int k = 0; k < 4; k++) {
        float z = ((const float*)&v)[k] * sc;
        float u = c0 * (z + c1 * z * z * z);
        float e = __expf(2.f * u);
        float th = 1.f - 2.f / (e + 1.f);      // tanh, inf-safe
        ((float*)&o)[k] = 0.5f * z * (1.f + th);
    }
    ((float4*)out)[i] = o;
}

extern "C" void kernel_launch(void* const* d_in, const int* in_sizes, int n_in,
                              void* d_out, int out_size, void* d_ws, size_t ws_size,
                              hipStream_t stream) {
    (void)in_sizes; (void)n_in; (void)out_size; (void)ws_size;
    const float* x      = (const float*)d_in[0];
    const float* ltau   = (const float*)d_in[1];
    const float* lblend = (const float*)d_in[2];
    float*    out   = (float*)d_out;
    // xnp (packed raw bf16, 16.8 MB) lives in d_out until gelu overwrites;
    // ws: msim (64 KB) + rnorm (64 KB).
    char*     xnp   = (char*)d_out;
    unsigned* msim  = (unsigned*)d_ws;
    float*    rnorm = (float*)((char*)d_ws + 65536);

    pack_kernel<<<B_ * T_ / 32, 256, 0, stream>>>(x, xnp, msim, rnorm);
    simmax_kernel<<<B_ * 72, 512, 0, stream>>>(xnp, rnorm, msim);
    gelu_kernel<<<(B_ * T_ * D_ / 4) / 256, 256, 0, stream>>>(
        x, msim, rnorm, ltau, lblend, out);
}